// Round 1
// baseline (829.705 us; speedup 1.0000x reference)
//
#include <hip/hip_runtime.h>

#define NEG_SLOPE 0.2f

static __device__ __forceinline__ float leaky(float x){ return x > 0.f ? x : NEG_SLOPE * x; }

// ---------------- CSR build ----------------

__global__ void deg_kernel(const int* __restrict__ edges, int* __restrict__ deg, int E){
  int i = blockIdx.x * 256 + threadIdx.x;
  if (i < E) atomicAdd(&deg[edges[2*i + 1]], 1);
}

__global__ __launch_bounds__(1024) void scan_kernel(const int* __restrict__ deg,
    int* __restrict__ row_ptr, int* __restrict__ cursor, float* __restrict__ inv, int n){
  __shared__ int stot[16];
  __shared__ int sCarry;
  int t = threadIdx.x;
  int lane = t & 63, wid = t >> 6;
  if (t == 0) sCarry = 0;
  __syncthreads();
  for (int base = 0; base < n; base += 1024){
    int i = base + t;
    int v = (i < n) ? deg[i] : 0;
    int sc = v;
    #pragma unroll
    for (int off = 1; off < 64; off <<= 1){
      int x = __shfl_up(sc, off);
      if (lane >= off) sc += x;
    }
    if (lane == 63) stot[wid] = sc;
    __syncthreads();
    if (wid == 0){
      int tv = (lane < 16) ? stot[lane] : 0;
      #pragma unroll
      for (int off = 1; off < 16; off <<= 1){
        int x = __shfl_up(tv, off);
        if (lane >= off) tv += x;
      }
      if (lane < 16) stot[lane] = tv;
    }
    __syncthreads();
    int c = sCarry;
    int wbase = (wid > 0) ? stot[wid - 1] : 0;
    int excl = c + wbase + (sc - v);
    if (i < n){
      row_ptr[i] = excl;
      cursor[i]  = excl;
      inv[i] = (v > 0) ? 1.0f / (float)v : 0.0f;
    }
    int total = stot[15];
    __syncthreads();
    if (t == 0) sCarry = c + total;
    __syncthreads();
  }
  if (t == 0) row_ptr[n] = sCarry;
}

__global__ void scatter_kernel(const int* __restrict__ edges, int* __restrict__ cursor,
                               int* __restrict__ col, int E){
  int i = blockIdx.x * 256 + threadIdx.x;
  if (i < E){
    int s = edges[2*i], d = edges[2*i + 1];
    int p = atomicAdd(&cursor[d], 1);
    col[p] = s;
  }
}

// ---------------- f32 GEMM: C = A(MxK) @ W(KxN) + bias ----------------
// 128x128 block tile, 256 threads, 8x8 per thread, BK=32.

__global__ __launch_bounds__(256) void gemm_bias_kernel(const float* __restrict__ A,
    const float* __restrict__ W, const float* __restrict__ bias,
    float* __restrict__ C, int M, int K, int N){
  __shared__ float As[32][129];   // As[k][m]
  __shared__ float Bs[32][132];   // Bs[k][n]
  int tid = threadIdx.x;
  int tx = tid & 15, ty = tid >> 4;
  int blockRow = blockIdx.x * 128;
  int blockCol = blockIdx.y * 128;

  float acc[8][8];
  #pragma unroll
  for (int i = 0; i < 8; i++)
    #pragma unroll
    for (int j = 0; j < 8; j++) acc[i][j] = 0.f;

  int kTiles = K >> 5;
  for (int kt = 0; kt < kTiles; ++kt){
    int k0 = kt << 5;
    // A tile 128x32 (transposed into As[k][m])
    #pragma unroll
    for (int q = 0; q < 4; q++){
      int r  = (tid >> 3) + 32 * q;
      int kc = (tid & 7) * 4;
      int gr = blockRow + r;
      float4 v = make_float4(0.f, 0.f, 0.f, 0.f);
      if (gr < M) v = *(const float4*)(A + (size_t)gr * K + k0 + kc);
      As[kc + 0][r] = v.x; As[kc + 1][r] = v.y;
      As[kc + 2][r] = v.z; As[kc + 3][r] = v.w;
    }
    // B tile 32x128
    #pragma unroll
    for (int q = 0; q < 4; q++){
      int lin = tid + 256 * q;        // 0..1023
      int kr = lin >> 5;              // 0..31
      int nc = (lin & 31) * 4;        // 0..124
      float4 v = *(const float4*)(W + (size_t)(k0 + kr) * N + blockCol + nc);
      *(float4*)&Bs[kr][nc] = v;
    }
    __syncthreads();
    #pragma unroll
    for (int k = 0; k < 32; k++){
      float a[8], b[8];
      #pragma unroll
      for (int i = 0; i < 8; i++) a[i] = As[k][ty * 8 + i];
      float4 b0 = *(float4*)&Bs[k][tx * 8];
      float4 b1 = *(float4*)&Bs[k][tx * 8 + 4];
      b[0] = b0.x; b[1] = b0.y; b[2] = b0.z; b[3] = b0.w;
      b[4] = b1.x; b[5] = b1.y; b[6] = b1.z; b[7] = b1.w;
      #pragma unroll
      for (int i = 0; i < 8; i++)
        #pragma unroll
        for (int j = 0; j < 8; j++)
          acc[i][j] += a[i] * b[j];
    }
    __syncthreads();
  }

  #pragma unroll
  for (int i = 0; i < 8; i++){
    int gr = blockRow + ty * 8 + i;
    if (gr >= M) continue;
    #pragma unroll
    for (int j = 0; j < 8; j += 4){
      int gc = blockCol + tx * 8 + j;
      float4 o;
      o.x = acc[i][j + 0] + bias[gc + 0];
      o.y = acc[i][j + 1] + bias[gc + 1];
      o.z = acc[i][j + 2] + bias[gc + 2];
      o.w = acc[i][j + 3] + bias[gc + 3];
      *(float4*)(C + (size_t)gr * N + gc) = o;
    }
  }
}

// ---------------- SpMM (CSR gather) + fused epilogue ----------------
// One 64-lane wave per dst row. F=256: float4/lane.

__global__ __launch_bounds__(256) void spmm_leaky_kernel(const float* __restrict__ sup,
    const int* __restrict__ row_ptr, const int* __restrict__ col,
    const float* __restrict__ inv, float* __restrict__ out, int n){
  int gw = (blockIdx.x * 256 + threadIdx.x) >> 6;
  int lane = threadIdx.x & 63;
  if (gw >= n) return;
  int s = row_ptr[gw], e = row_ptr[gw + 1];
  float ir = inv[gw];
  int off = lane * 4;
  float4 acc = make_float4(0.f, 0.f, 0.f, 0.f);
  for (int i = s; i < e; ++i){
    int c = col[i];
    const float4 v = *(const float4*)(sup + (size_t)c * 256 + off);
    acc.x += v.x; acc.y += v.y; acc.z += v.z; acc.w += v.w;
  }
  acc.x = leaky(acc.x * ir); acc.y = leaky(acc.y * ir);
  acc.z = leaky(acc.z * ir); acc.w = leaky(acc.w * ir);
  *(float4*)(out + (size_t)gw * 256 + off) = acc;
}

// F=128: float2/lane, fused inv-scale + L2 row-normalize.
__global__ __launch_bounds__(256) void spmm_norm_kernel(const float* __restrict__ sup,
    const int* __restrict__ row_ptr, const int* __restrict__ col,
    const float* __restrict__ inv, float* __restrict__ out, int n){
  int gw = (blockIdx.x * 256 + threadIdx.x) >> 6;
  int lane = threadIdx.x & 63;
  if (gw >= n) return;
  int s = row_ptr[gw], e = row_ptr[gw + 1];
  float ir = inv[gw];
  int off = lane * 2;
  float2 acc = make_float2(0.f, 0.f);
  for (int i = s; i < e; ++i){
    int c = col[i];
    const float2 v = *(const float2*)(sup + (size_t)c * 128 + off);
    acc.x += v.x; acc.y += v.y;
  }
  float v0 = acc.x * ir, v1 = acc.y * ir;
  float ss = v0 * v0 + v1 * v1;
  #pragma unroll
  for (int o = 32; o > 0; o >>= 1) ss += __shfl_xor(ss, o);
  float scale = 1.0f / fmaxf(sqrtf(ss), 1e-12f);
  out[(size_t)gw * 128 + off]     = v0 * scale;
  out[(size_t)gw * 128 + off + 1] = v1 * scale;
}

// ---------------- launch ----------------

extern "C" void kernel_launch(void* const* d_in, const int* in_sizes, int n_in,
                              void* d_out, int out_size, void* d_ws, size_t ws_size,
                              hipStream_t stream){
  const float* x  = (const float*)d_in[0];
  const float* W1 = (const float*)d_in[1];
  const float* b1 = (const float*)d_in[2];
  const float* W2 = (const float*)d_in[3];
  const float* b2 = (const float*)d_in[4];
  const float* W3 = (const float*)d_in[5];
  const float* b3 = (const float*)d_in[6];
  const int* edges = (const int*)d_in[7];
  int N = in_sizes[0] / 128;
  int E = in_sizes[7] / 2;

  char* w = (char*)d_ws;
  size_t off = 0;
  auto alloc = [&](size_t bytes)->char*{
    char* p = w + off;
    off = (off + bytes + 255) & ~(size_t)255;
    return p;
  };
  int*   deg     = (int*)  alloc((size_t)N * 4);
  float* inv     = (float*)alloc((size_t)N * 4);
  int*   row_ptr = (int*)  alloc(((size_t)N + 1) * 4);
  int*   cursor  = (int*)  alloc((size_t)N * 4);
  int*   colidx  = (int*)  alloc((size_t)E * 4);
  float* bufA    = (float*)alloc((size_t)N * 256 * 4);
  float* bufB    = (float*)alloc((size_t)N * 256 * 4);

  hipMemsetAsync(deg, 0, (size_t)N * 4, stream);
  int gE = (E + 255) / 256;
  deg_kernel<<<gE, 256, 0, stream>>>(edges, deg, E);
  scan_kernel<<<1, 1024, 0, stream>>>(deg, row_ptr, cursor, inv, N);
  scatter_kernel<<<gE, 256, 0, stream>>>(edges, cursor, colidx, E);

  dim3 g12((N + 127) / 128, 2);
  dim3 g3 ((N + 127) / 128, 1);
  int gS = (N * 64 + 255) / 256;

  // layer 1: support = x@W1+b1 ; h1 = leaky(inv * A^T support)
  gemm_bias_kernel<<<g12, 256, 0, stream>>>(x, W1, b1, bufA, N, 128, 256);
  spmm_leaky_kernel<<<gS, 256, 0, stream>>>(bufA, row_ptr, colidx, inv, bufB, N);
  // layer 2
  gemm_bias_kernel<<<g12, 256, 0, stream>>>(bufB, W2, b2, bufA, N, 256, 256);
  spmm_leaky_kernel<<<gS, 256, 0, stream>>>(bufA, row_ptr, colidx, inv, bufB, N);
  // layer 3 + normalize
  gemm_bias_kernel<<<g3, 256, 0, stream>>>(bufB, W3, b3, bufA, N, 256, 128);
  spmm_norm_kernel<<<gS, 256, 0, stream>>>(bufA, row_ptr, colidx, inv, (float*)d_out, N);
}

// Round 3
// 667.352 us; speedup vs baseline: 1.2433x; 1.2433x over previous
//
#include <hip/hip_runtime.h>

#define NEG_SLOPE 0.2f

typedef __attribute__((ext_vector_type(8))) short short8;
typedef __attribute__((ext_vector_type(4))) float floatx4;

static __device__ __forceinline__ float leaky(float x){ return x > 0.f ? x : NEG_SLOPE * x; }

static __device__ __forceinline__ unsigned short bf16_rne(float x){
  unsigned u = __float_as_uint(x);
  unsigned r = (u + 0x7fffu + ((u >> 16) & 1u)) >> 16;
  return (unsigned short)r;
}
static __device__ __forceinline__ float bf16_to_f(unsigned short h){
  return __uint_as_float(((unsigned)h) << 16);
}

// ---------------- CSR build ----------------

__global__ void deg_kernel(const int* __restrict__ edges, int* __restrict__ deg, int E){
  int i = blockIdx.x * 256 + threadIdx.x;
  if (i < E) atomicAdd(&deg[edges[2*i + 1]], 1);
}

__global__ __launch_bounds__(1024) void scan_kernel(const int* __restrict__ deg,
    int* __restrict__ row_ptr, int* __restrict__ cursor, float* __restrict__ inv, int n){
  __shared__ int stot[16];
  __shared__ int sCarry;
  int t = threadIdx.x;
  int lane = t & 63, wid = t >> 6;
  if (t == 0) sCarry = 0;
  __syncthreads();
  for (int base = 0; base < n; base += 1024){
    int i = base + t;
    int v = (i < n) ? deg[i] : 0;
    int sc = v;
    #pragma unroll
    for (int off = 1; off < 64; off <<= 1){
      int x = __shfl_up(sc, off);
      if (lane >= off) sc += x;
    }
    if (lane == 63) stot[wid] = sc;
    __syncthreads();
    if (wid == 0){
      int tv = (lane < 16) ? stot[lane] : 0;
      #pragma unroll
      for (int off = 1; off < 16; off <<= 1){
        int x = __shfl_up(tv, off);
        if (lane >= off) tv += x;
      }
      if (lane < 16) stot[lane] = tv;
    }
    __syncthreads();
    int c = sCarry;
    int wbase = (wid > 0) ? stot[wid - 1] : 0;
    int excl = c + wbase + (sc - v);
    if (i < n){
      row_ptr[i] = excl;
      cursor[i]  = excl;
      inv[i] = (v > 0) ? 1.0f / (float)v : 0.0f;
    }
    int total = stot[15];
    __syncthreads();
    if (t == 0) sCarry = c + total;
    __syncthreads();
  }
  if (t == 0) row_ptr[n] = sCarry;
}

__global__ void scatter_kernel(const int* __restrict__ edges, int* __restrict__ cursor,
                               int* __restrict__ col, int E){
  int i = blockIdx.x * 256 + threadIdx.x;
  if (i < E){
    int s = edges[2*i], d = edges[2*i + 1];
    int p = atomicAdd(&cursor[d], 1);
    col[p] = s;
  }
}

// Sort each row's column indices -> deterministic summation order in SpMM,
// independent of atomic scatter ordering (required: harness re-validates
// after timed replays; f32 sum order must be call-invariant).
__global__ void sortrows_kernel(const int* __restrict__ row_ptr, int* __restrict__ col, int n){
  int r = blockIdx.x * 256 + threadIdx.x;
  if (r >= n) return;
  int s = row_ptr[r], e = row_ptr[r + 1];
  for (int i = s + 1; i < e; ++i){
    int v = col[i];
    int j = i - 1;
    while (j >= s && col[j] > v){ col[j + 1] = col[j]; --j; }
    col[j + 1] = v;
  }
}

// ---------------- W prep: transpose + split into bf16 hi/lo ----------------

__global__ void wprep_kernel(const float* __restrict__ W, unsigned short* __restrict__ hi,
                             unsigned short* __restrict__ lo, int K, int N){
  int i = blockIdx.x * 256 + threadIdx.x;
  if (i >= K * N) return;
  int k = i / N, n = i - k * N;
  float a = W[i];
  unsigned short h = bf16_rne(a);
  float r = a - bf16_to_f(h);
  hi[(size_t)n * K + k] = h;
  lo[(size_t)n * K + k] = bf16_rne(r);
}

// ---------------- MFMA GEMM: C = A(MxK,f32) @ W(KxN) + bias ----------------
// Split-bf16: A = Ah+Al, B = Bh+Bl; C ~= AhBh + AlBh + AhBl (f32 accum).
// 128x128 block tile, 4 waves (2x2), wave tile 64x64, BK=32.
// LDS rows: [hi(32 bf16) | lo(32 bf16)] = 128B/row, XOR-swizzled by (row&7)<<4.

__global__ __launch_bounds__(256) void gemm_mfma_kernel(const float* __restrict__ A,
    const unsigned short* __restrict__ Bt_hi, const unsigned short* __restrict__ Bt_lo,
    const float* __restrict__ bias, float* __restrict__ C, int M, int K, int N){
  __shared__ unsigned short sA[128 * 64];
  __shared__ unsigned short sB[128 * 64];
  const int tid  = threadIdx.x;
  const int lane = tid & 63;
  const int wid  = tid >> 6;
  const int wrow = wid >> 1;        // 0..1
  const int wcol = wid & 1;         // 0..1
  const int br = blockIdx.x * 128;
  const int bc = blockIdx.y * 128;

  floatx4 acc[4][4];
  #pragma unroll
  for (int i = 0; i < 4; i++)
    #pragma unroll
    for (int j = 0; j < 4; j++) acc[i][j] = (floatx4){0.f, 0.f, 0.f, 0.f};

  const int arow = tid >> 1;        // 0..127
  const int asel = tid & 1;         // k-half for A, hi/lo select for B
  char* pa = (char*)sA;
  char* pb = (char*)sB;
  const int g16 = (lane >> 4) << 4; // fragment granule byte offset

  for (int k0 = 0; k0 < K; k0 += 32){
    // ---- stage A: rows br..br+127, k0..k0+31, f32 -> bf16 hi/lo ----
    {
      int grow = br + arow;
      float f[16];
      if (grow < M){
        const float* ap = A + (size_t)grow * K + k0 + asel * 16;
        #pragma unroll
        for (int q = 0; q < 4; q++){
          float4 v = *(const float4*)(ap + q * 4);
          f[q*4+0] = v.x; f[q*4+1] = v.y; f[q*4+2] = v.z; f[q*4+3] = v.w;
        }
      } else {
        #pragma unroll
        for (int q = 0; q < 16; q++) f[q] = 0.f;
      }
      short8 hv0, hv1, lv0, lv1;
      #pragma unroll
      for (int q = 0; q < 8; q++){
        unsigned short h0 = bf16_rne(f[q]);
        unsigned short h1 = bf16_rne(f[q+8]);
        hv0[q] = (short)h0; hv1[q] = (short)h1;
        lv0[q] = (short)bf16_rne(f[q]   - bf16_to_f(h0));
        lv1[q] = (short)bf16_rne(f[q+8] - bf16_to_f(h1));
      }
      unsigned rb  = arow * 128;
      unsigned swz = (arow & 7) << 4;
      unsigned o   = asel * 32;
      *(short8*)(pa + (rb + ((o +  0) ^ swz))) = hv0;
      *(short8*)(pa + (rb + ((o + 16) ^ swz))) = hv1;
      *(short8*)(pa + (rb + ((64 + o +  0) ^ swz))) = lv0;
      *(short8*)(pa + (rb + ((64 + o + 16) ^ swz))) = lv1;
    }
    // ---- stage B: cols bc..bc+127 from pre-transposed bf16 [N][K] ----
    {
      int colb = tid >> 1;
      const unsigned short* src = (asel ? Bt_lo : Bt_hi) + (size_t)(bc + colb) * K + k0;
      short8 v0 = *(const short8*)(src + 0);
      short8 v1 = *(const short8*)(src + 8);
      short8 v2 = *(const short8*)(src + 16);
      short8 v3 = *(const short8*)(src + 24);
      unsigned rb  = colb * 128;
      unsigned swz = (colb & 7) << 4;
      unsigned o   = asel * 64;
      *(short8*)(pb + (rb + ((o +  0) ^ swz))) = v0;
      *(short8*)(pb + (rb + ((o + 16) ^ swz))) = v1;
      *(short8*)(pb + (rb + ((o + 32) ^ swz))) = v2;
      *(short8*)(pb + (rb + ((o + 48) ^ swz))) = v3;
    }
    __syncthreads();
    // ---- fragments + MFMA ----
    short8 bh[4], bl[4];
    #pragma unroll
    for (int nf = 0; nf < 4; nf++){
      int coll = wcol * 64 + nf * 16 + (lane & 15);
      unsigned sw = (coll & 7) << 4;
      const char* pr = pb + coll * 128;
      bh[nf] = *(const short8*)(pr + ((g16) ^ sw));
      bl[nf] = *(const short8*)(pr + ((64 + g16) ^ sw));
    }
    #pragma unroll
    for (int mf = 0; mf < 4; mf++){
      int rowl = wrow * 64 + mf * 16 + (lane & 15);
      unsigned sw = (rowl & 7) << 4;
      const char* pr = pa + rowl * 128;
      short8 ah = *(const short8*)(pr + ((g16) ^ sw));
      short8 al = *(const short8*)(pr + ((64 + g16) ^ sw));
      #pragma unroll
      for (int nf = 0; nf < 4; nf++){
        acc[mf][nf] = __builtin_amdgcn_mfma_f32_16x16x32_bf16(ah, bh[nf], acc[mf][nf], 0, 0, 0);
        acc[mf][nf] = __builtin_amdgcn_mfma_f32_16x16x32_bf16(al, bh[nf], acc[mf][nf], 0, 0, 0);
        acc[mf][nf] = __builtin_amdgcn_mfma_f32_16x16x32_bf16(ah, bl[nf], acc[mf][nf], 0, 0, 0);
      }
    }
    __syncthreads();
  }

  // ---- epilogue: C = acc + bias ----
  const int r0 = br + wrow * 64;
  const int c0 = bc + wcol * 64;
  #pragma unroll
  for (int nf = 0; nf < 4; nf++){
    int col = c0 + nf * 16 + (lane & 15);
    float bv = bias[col];
    #pragma unroll
    for (int mf = 0; mf < 4; mf++){
      int rbase = r0 + mf * 16 + ((lane >> 4) << 2);
      #pragma unroll
      for (int j = 0; j < 4; j++){
        int r = rbase + j;
        if (r < M) C[(size_t)r * N + col] = acc[mf][nf][j] + bv;
      }
    }
  }
}

// ---------------- SpMM (CSR gather) + fused epilogue ----------------

__global__ __launch_bounds__(256) void spmm_leaky_kernel(const float* __restrict__ sup,
    const int* __restrict__ row_ptr, const int* __restrict__ col,
    const float* __restrict__ inv, float* __restrict__ out, int n){
  int gw = (blockIdx.x * 256 + threadIdx.x) >> 6;
  int lane = threadIdx.x & 63;
  if (gw >= n) return;
  int s = row_ptr[gw], e = row_ptr[gw + 1];
  float ir = inv[gw];
  int off = lane * 4;
  float4 acc = make_float4(0.f, 0.f, 0.f, 0.f);
  for (int i = s; i < e; ++i){
    int c = col[i];
    const float4 v = *(const float4*)(sup + (size_t)c * 256 + off);
    acc.x += v.x; acc.y += v.y; acc.z += v.z; acc.w += v.w;
  }
  acc.x = leaky(acc.x * ir); acc.y = leaky(acc.y * ir);
  acc.z = leaky(acc.z * ir); acc.w = leaky(acc.w * ir);
  *(float4*)(out + (size_t)gw * 256 + off) = acc;
}

__global__ __launch_bounds__(256) void spmm_norm_kernel(const float* __restrict__ sup,
    const int* __restrict__ row_ptr, const int* __restrict__ col,
    const float* __restrict__ inv, float* __restrict__ out, int n){
  int gw = (blockIdx.x * 256 + threadIdx.x) >> 6;
  int lane = threadIdx.x & 63;
  if (gw >= n) return;
  int s = row_ptr[gw], e = row_ptr[gw + 1];
  float ir = inv[gw];
  int off = lane * 2;
  float2 acc = make_float2(0.f, 0.f);
  for (int i = s; i < e; ++i){
    int c = col[i];
    const float2 v = *(const float2*)(sup + (size_t)c * 128 + off);
    acc.x += v.x; acc.y += v.y;
  }
  float v0 = acc.x * ir, v1 = acc.y * ir;
  float ss = v0 * v0 + v1 * v1;
  #pragma unroll
  for (int o = 32; o > 0; o >>= 1) ss += __shfl_xor(ss, o);
  float scale = 1.0f / fmaxf(sqrtf(ss), 1e-12f);
  out[(size_t)gw * 128 + off]     = v0 * scale;
  out[(size_t)gw * 128 + off + 1] = v1 * scale;
}

// ---------------- launch ----------------

extern "C" void kernel_launch(void* const* d_in, const int* in_sizes, int n_in,
                              void* d_out, int out_size, void* d_ws, size_t ws_size,
                              hipStream_t stream){
  const float* x  = (const float*)d_in[0];
  const float* W1 = (const float*)d_in[1];
  const float* b1 = (const float*)d_in[2];
  const float* W2 = (const float*)d_in[3];
  const float* b2 = (const float*)d_in[4];
  const float* W3 = (const float*)d_in[5];
  const float* b3 = (const float*)d_in[6];
  const int* edges = (const int*)d_in[7];
  int N = in_sizes[0] / 128;
  int E = in_sizes[7] / 2;

  char* w = (char*)d_ws;
  size_t off = 0;
  auto alloc = [&](size_t bytes)->char*{
    char* p = w + off;
    off = (off + bytes + 255) & ~(size_t)255;
    return p;
  };
  int*   deg     = (int*)  alloc((size_t)N * 4);
  float* inv     = (float*)alloc((size_t)N * 4);
  int*   row_ptr = (int*)  alloc(((size_t)N + 1) * 4);
  int*   cursor  = (int*)  alloc((size_t)N * 4);
  int*   colidx  = (int*)  alloc((size_t)E * 4);
  unsigned short* wt1h = (unsigned short*)alloc((size_t)128 * 256 * 2);
  unsigned short* wt1l = (unsigned short*)alloc((size_t)128 * 256 * 2);
  unsigned short* wt2h = (unsigned short*)alloc((size_t)256 * 256 * 2);
  unsigned short* wt2l = (unsigned short*)alloc((size_t)256 * 256 * 2);
  unsigned short* wt3h = (unsigned short*)alloc((size_t)256 * 128 * 2);
  unsigned short* wt3l = (unsigned short*)alloc((size_t)256 * 128 * 2);
  float* bufA    = (float*)alloc((size_t)N * 256 * 4);
  float* bufB    = (float*)alloc((size_t)N * 256 * 4);

  hipMemsetAsync(deg, 0, (size_t)N * 4, stream);
  int gE = (E + 255) / 256;
  deg_kernel<<<gE, 256, 0, stream>>>(edges, deg, E);
  scan_kernel<<<1, 1024, 0, stream>>>(deg, row_ptr, cursor, inv, N);
  scatter_kernel<<<gE, 256, 0, stream>>>(edges, cursor, colidx, E);
  sortrows_kernel<<<(N + 255)/256, 256, 0, stream>>>(row_ptr, colidx, N);

  wprep_kernel<<<(128*256 + 255)/256, 256, 0, stream>>>(W1, wt1h, wt1l, 128, 256);
  wprep_kernel<<<(256*256 + 255)/256, 256, 0, stream>>>(W2, wt2h, wt2l, 256, 256);
  wprep_kernel<<<(256*128 + 255)/256, 256, 0, stream>>>(W3, wt3h, wt3l, 256, 128);

  int gm = (N + 127) / 128;
  dim3 g12(gm, 2);
  dim3 g3 (gm, 1);
  int gS = (N * 64 + 255) / 256;

  // layer 1: support = x@W1+b1 ; h1 = leaky(inv * A^T support)
  gemm_mfma_kernel<<<g12, 256, 0, stream>>>(x, wt1h, wt1l, b1, bufA, N, 128, 256);
  spmm_leaky_kernel<<<gS, 256, 0, stream>>>(bufA, row_ptr, colidx, inv, bufB, N);
  // layer 2
  gemm_mfma_kernel<<<g12, 256, 0, stream>>>(bufB, wt2h, wt2l, b2, bufA, N, 256, 256);
  spmm_leaky_kernel<<<gS, 256, 0, stream>>>(bufA, row_ptr, colidx, inv, bufB, N);
  // layer 3 + normalize
  gemm_mfma_kernel<<<g3, 256, 0, stream>>>(bufB, wt3h, wt3l, b3, bufA, N, 256, 128);
  spmm_norm_kernel<<<gS, 256, 0, stream>>>(bufA, row_ptr, colidx, inv, (float*)d_out, N);
}

// Round 4
// 557.407 us; speedup vs baseline: 1.4885x; 1.1972x over previous
//
#include <hip/hip_runtime.h>

#define NEG_SLOPE 0.2f

typedef __attribute__((ext_vector_type(8))) short short8;
typedef __attribute__((ext_vector_type(4))) float floatx4;
typedef unsigned short ushort_t;

static __device__ __forceinline__ float leaky(float x){ return x > 0.f ? x : NEG_SLOPE * x; }

static __device__ __forceinline__ unsigned short bf16_rne(float x){
  unsigned u = __float_as_uint(x);
  unsigned r = (u + 0x7fffu + ((u >> 16) & 1u)) >> 16;
  return (unsigned short)r;
}
static __device__ __forceinline__ float bf16_to_f(unsigned short h){
  return __uint_as_float(((unsigned)h) << 16);
}

// ---------------- CSR build ----------------

__global__ void deg_kernel(const int* __restrict__ edges, int* __restrict__ deg, int E){
  int i = blockIdx.x * 256 + threadIdx.x;
  if (i < E) atomicAdd(&deg[edges[2*i + 1]], 1);
}

__global__ __launch_bounds__(1024) void scan_kernel(const int* __restrict__ deg,
    int* __restrict__ row_ptr, int* __restrict__ cursor, float* __restrict__ inv, int n){
  __shared__ int stot[16];
  __shared__ int sCarry;
  int t = threadIdx.x;
  int lane = t & 63, wid = t >> 6;
  if (t == 0) sCarry = 0;
  __syncthreads();
  for (int base = 0; base < n; base += 1024){
    int i = base + t;
    int v = (i < n) ? deg[i] : 0;
    int sc = v;
    #pragma unroll
    for (int off = 1; off < 64; off <<= 1){
      int x = __shfl_up(sc, off);
      if (lane >= off) sc += x;
    }
    if (lane == 63) stot[wid] = sc;
    __syncthreads();
    if (wid == 0){
      int tv = (lane < 16) ? stot[lane] : 0;
      #pragma unroll
      for (int off = 1; off < 16; off <<= 1){
        int x = __shfl_up(tv, off);
        if (lane >= off) tv += x;
      }
      if (lane < 16) stot[lane] = tv;
    }
    __syncthreads();
    int c = sCarry;
    int wbase = (wid > 0) ? stot[wid - 1] : 0;
    int excl = c + wbase + (sc - v);
    if (i < n){
      row_ptr[i] = excl;
      cursor[i]  = excl;
      inv[i] = (v > 0) ? 1.0f / (float)v : 0.0f;
    }
    int total = stot[15];
    __syncthreads();
    if (t == 0) sCarry = c + total;
    __syncthreads();
  }
  if (t == 0) row_ptr[n] = sCarry;
}

__global__ void scatter_kernel(const int* __restrict__ edges, int* __restrict__ cursor,
                               int* __restrict__ col, int E){
  int i = blockIdx.x * 256 + threadIdx.x;
  if (i < E){
    int s = edges[2*i], d = edges[2*i + 1];
    int p = atomicAdd(&cursor[d], 1);
    col[p] = s;
  }
}

// Deterministic col order per row (harness re-validates after replays; f32 sum
// order must be call-invariant). Wave-bitonic sort, all in registers.
__global__ __launch_bounds__(256) void sortrows_kernel(const int* __restrict__ row_ptr,
                                                       int* __restrict__ col, int n){
  int gw = (blockIdx.x * 256 + threadIdx.x) >> 6;
  int lane = threadIdx.x & 63;
  if (gw >= n) return;
  int s = row_ptr[gw], e = row_ptr[gw + 1];
  int len = e - s;
  if (len <= 1) return;
  if (len <= 64){
    int v = (lane < len) ? col[s + lane] : 0x7fffffff;
    #pragma unroll
    for (int k = 2; k <= 64; k <<= 1){
      #pragma unroll
      for (int j = k >> 1; j > 0; j >>= 1){
        int o = __shfl_xor(v, j);
        bool dirUp = ((lane & k) == 0);
        bool takeMin = (((lane & j) == 0) == dirUp);
        v = takeMin ? min(v, o) : max(v, o);
      }
    }
    if (lane < len) col[s + lane] = v;
  } else if (lane == 0){
    for (int i = s + 1; i < e; ++i){
      int v = col[i];
      int j = i - 1;
      while (j >= s && col[j] > v){ col[j + 1] = col[j]; --j; }
      col[j + 1] = v;
    }
  }
}

// ---------------- W prep: transpose + split into bf16 hi/lo planes ----------------

__global__ void wprep_kernel(const float* __restrict__ W, ushort_t* __restrict__ hi,
                             ushort_t* __restrict__ lo, int K, int N){
  int i = blockIdx.x * 256 + threadIdx.x;
  if (i >= K * N) return;
  int k = i / N, n = i - k * N;
  float a = W[i];
  unsigned short h = bf16_rne(a);
  float r = a - bf16_to_f(h);
  hi[(size_t)n * K + k] = h;
  lo[(size_t)n * K + k] = bf16_rne(r);
}

// ---------------- MFMA GEMM ----------------
// A: [M][2K] ushort pair rows (hi[0..K) | lo[0..K)) -- preconverted by producer.
// Split-bf16 3-term: AhBh + AlBh + AhBl, f32 accum.
// 128x128 tile, 4 waves 2x2, BK=32. LDS rows 128B, XOR-swizzle (row&7)<<4.
// L1 mode: C -> bf16 pair [M][2N], leaky, bias masked by (inv>0).
// else:    C -> f32 [M][N], plain bias.

template<bool L1>
__global__ __launch_bounds__(256) void gemm_mfma_kernel(
    const ushort_t* __restrict__ A,
    const ushort_t* __restrict__ Bt_hi, const ushort_t* __restrict__ Bt_lo,
    const float* __restrict__ bias, const float* __restrict__ invv,
    float* __restrict__ Cf, ushort_t* __restrict__ Cp,
    int M, int K, int N){
  __shared__ ushort_t sA[128 * 64];
  __shared__ ushort_t sB[128 * 64];
  const int tid  = threadIdx.x;
  const int lane = tid & 63;
  const int wid  = tid >> 6;
  const int wrow = wid >> 1;
  const int wcol = wid & 1;
  const int br = blockIdx.x * 128;
  const int bc = blockIdx.y * 128;

  floatx4 acc[4][4];
  #pragma unroll
  for (int i = 0; i < 4; i++)
    #pragma unroll
    for (int j = 0; j < 4; j++) acc[i][j] = (floatx4){0.f, 0.f, 0.f, 0.f};

  const int arow = tid >> 1;
  const int asel = tid & 1;
  char* pa = (char*)sA;
  char* pb = (char*)sB;
  const int g16 = (lane >> 4) << 4;

  for (int k0 = 0; k0 < K; k0 += 32){
    // ---- stage A: preconverted pair rows, no VALU conversion ----
    {
      int grow = br + arow;
      short8 hv0, hv1, lv0, lv1;
      if (grow < M){
        const ushort_t* ap = A + (size_t)grow * (2 * K) + k0 + asel * 16;
        hv0 = *(const short8*)(ap);
        hv1 = *(const short8*)(ap + 8);
        lv0 = *(const short8*)(ap + K);
        lv1 = *(const short8*)(ap + K + 8);
      } else {
        hv0 = hv1 = lv0 = lv1 = (short8){0,0,0,0,0,0,0,0};
      }
      unsigned rb  = arow * 128;
      unsigned swz = (arow & 7) << 4;
      unsigned o   = asel * 32;
      *(short8*)(pa + (rb + ((o +  0) ^ swz))) = hv0;
      *(short8*)(pa + (rb + ((o + 16) ^ swz))) = hv1;
      *(short8*)(pa + (rb + ((64 + o +  0) ^ swz))) = lv0;
      *(short8*)(pa + (rb + ((64 + o + 16) ^ swz))) = lv1;
    }
    // ---- stage B ----
    {
      int colb = tid >> 1;
      const ushort_t* src = (asel ? Bt_lo : Bt_hi) + (size_t)(bc + colb) * K + k0;
      short8 v0 = *(const short8*)(src + 0);
      short8 v1 = *(const short8*)(src + 8);
      short8 v2 = *(const short8*)(src + 16);
      short8 v3 = *(const short8*)(src + 24);
      unsigned rb  = colb * 128;
      unsigned swz = (colb & 7) << 4;
      unsigned o   = asel * 64;
      *(short8*)(pb + (rb + ((o +  0) ^ swz))) = v0;
      *(short8*)(pb + (rb + ((o + 16) ^ swz))) = v1;
      *(short8*)(pb + (rb + ((o + 32) ^ swz))) = v2;
      *(short8*)(pb + (rb + ((o + 48) ^ swz))) = v3;
    }
    __syncthreads();
    short8 bh[4], bl[4];
    #pragma unroll
    for (int nf = 0; nf < 4; nf++){
      int coll = wcol * 64 + nf * 16 + (lane & 15);
      unsigned sw = (coll & 7) << 4;
      const char* pr = pb + coll * 128;
      bh[nf] = *(const short8*)(pr + ((g16) ^ sw));
      bl[nf] = *(const short8*)(pr + ((64 + g16) ^ sw));
    }
    #pragma unroll
    for (int mf = 0; mf < 4; mf++){
      int rowl = wrow * 64 + mf * 16 + (lane & 15);
      unsigned sw = (rowl & 7) << 4;
      const char* pr = pa + rowl * 128;
      short8 ah = *(const short8*)(pr + ((g16) ^ sw));
      short8 al = *(const short8*)(pr + ((64 + g16) ^ sw));
      #pragma unroll
      for (int nf = 0; nf < 4; nf++){
        acc[mf][nf] = __builtin_amdgcn_mfma_f32_16x16x32_bf16(ah, bh[nf], acc[mf][nf], 0, 0, 0);
        acc[mf][nf] = __builtin_amdgcn_mfma_f32_16x16x32_bf16(al, bh[nf], acc[mf][nf], 0, 0, 0);
        acc[mf][nf] = __builtin_amdgcn_mfma_f32_16x16x32_bf16(ah, bl[nf], acc[mf][nf], 0, 0, 0);
      }
    }
    __syncthreads();
  }

  const int r0 = br + wrow * 64;
  const int c0 = bc + wcol * 64;
  #pragma unroll
  for (int nf = 0; nf < 4; nf++){
    int col = c0 + nf * 16 + (lane & 15);
    float bv = bias[col];
    #pragma unroll
    for (int mf = 0; mf < 4; mf++){
      int rbase = r0 + mf * 16 + ((lane >> 4) << 2);
      #pragma unroll
      for (int j = 0; j < 4; j++){
        int r = rbase + j;
        if (r >= M) continue;
        float v;
        if (L1){
          float m = (invv[r] > 0.f) ? 1.f : 0.f;
          v = leaky(acc[mf][nf][j] + m * bv);
          unsigned short h = bf16_rne(v);
          unsigned short l = bf16_rne(v - bf16_to_f(h));
          Cp[(size_t)r * (2 * N) + col]     = h;
          Cp[(size_t)r * (2 * N) + N + col] = l;
        } else {
          v = acc[mf][nf][j] + bv;
          Cf[(size_t)r * N + col] = v;
        }
      }
    }
  }
}

// ---------------- SpMM kernels (CSR gather, one wave per dst row) ----------------

// x (f32 [n][128]) -> t pair (ushort [n][256]); t = inv * sum x[src]
__global__ __launch_bounds__(256) void spmm128_pair_kernel(const float* __restrict__ x,
    const int* __restrict__ row_ptr, const int* __restrict__ col,
    const float* __restrict__ inv, ushort_t* __restrict__ out, int n){
  int gw = (blockIdx.x * 256 + threadIdx.x) >> 6;
  int lane = threadIdx.x & 63;
  if (gw >= n) return;
  int s = row_ptr[gw], e = row_ptr[gw + 1];
  float ir = inv[gw];
  int off = lane * 2;
  float2 a0 = make_float2(0.f, 0.f), a1 = make_float2(0.f, 0.f);
  int i = s;
  for (; i + 1 < e; i += 2){
    int c0 = col[i], c1 = col[i + 1];
    float2 v0 = *(const float2*)(x + (size_t)c0 * 128 + off);
    float2 v1 = *(const float2*)(x + (size_t)c1 * 128 + off);
    a0.x += v0.x; a0.y += v0.y;
    a1.x += v1.x; a1.y += v1.y;
  }
  if (i < e){
    int c0 = col[i];
    float2 v0 = *(const float2*)(x + (size_t)c0 * 128 + off);
    a0.x += v0.x; a0.y += v0.y;
  }
  float v0 = (a0.x + a1.x) * ir, v1 = (a0.y + a1.y) * ir;
  unsigned short h0 = bf16_rne(v0), h1 = bf16_rne(v1);
  unsigned short l0 = bf16_rne(v0 - bf16_to_f(h0));
  unsigned short l1 = bf16_rne(v1 - bf16_to_f(h1));
  ushort2 hv; hv.x = h0; hv.y = h1;
  ushort2 lv; lv.x = l0; lv.y = l1;
  *(ushort2*)(out + (size_t)gw * 256 + off)       = hv;
  *(ushort2*)(out + (size_t)gw * 256 + 128 + off) = lv;
}

// support (f32 [n][256]) -> h pair (ushort [n][512]); h = leaky(inv * sum)
__global__ __launch_bounds__(256) void spmm256_leaky_pair_kernel(const float* __restrict__ sup,
    const int* __restrict__ row_ptr, const int* __restrict__ col,
    const float* __restrict__ inv, ushort_t* __restrict__ out, int n){
  int gw = (blockIdx.x * 256 + threadIdx.x) >> 6;
  int lane = threadIdx.x & 63;
  if (gw >= n) return;
  int s = row_ptr[gw], e = row_ptr[gw + 1];
  float ir = inv[gw];
  int off = lane * 4;
  float4 a0 = make_float4(0.f,0.f,0.f,0.f), a1 = make_float4(0.f,0.f,0.f,0.f);
  int i = s;
  for (; i + 1 < e; i += 2){
    int c0 = col[i], c1 = col[i + 1];
    float4 v0 = *(const float4*)(sup + (size_t)c0 * 256 + off);
    float4 v1 = *(const float4*)(sup + (size_t)c1 * 256 + off);
    a0.x += v0.x; a0.y += v0.y; a0.z += v0.z; a0.w += v0.w;
    a1.x += v1.x; a1.y += v1.y; a1.z += v1.z; a1.w += v1.w;
  }
  if (i < e){
    int c0 = col[i];
    float4 v0 = *(const float4*)(sup + (size_t)c0 * 256 + off);
    a0.x += v0.x; a0.y += v0.y; a0.z += v0.z; a0.w += v0.w;
  }
  float f[4];
  f[0] = leaky((a0.x + a1.x) * ir); f[1] = leaky((a0.y + a1.y) * ir);
  f[2] = leaky((a0.z + a1.z) * ir); f[3] = leaky((a0.w + a1.w) * ir);
  ushort_t h[4], l[4];
  #pragma unroll
  for (int q = 0; q < 4; q++){
    h[q] = bf16_rne(f[q]);
    l[q] = bf16_rne(f[q] - bf16_to_f(h[q]));
  }
  ushort4 hv; hv.x=h[0]; hv.y=h[1]; hv.z=h[2]; hv.w=h[3];
  ushort4 lv; lv.x=l[0]; lv.y=l[1]; lv.z=l[2]; lv.w=l[3];
  *(ushort4*)(out + (size_t)gw * 512 + off)       = hv;
  *(ushort4*)(out + (size_t)gw * 512 + 256 + off) = lv;
}

// support (f32 [n][128]) -> out f32 [n][128]; inv-scale + L2 row-normalize
__global__ __launch_bounds__(256) void spmm_norm_kernel(const float* __restrict__ sup,
    const int* __restrict__ row_ptr, const int* __restrict__ col,
    const float* __restrict__ inv, float* __restrict__ out, int n){
  int gw = (blockIdx.x * 256 + threadIdx.x) >> 6;
  int lane = threadIdx.x & 63;
  if (gw >= n) return;
  int s = row_ptr[gw], e = row_ptr[gw + 1];
  float ir = inv[gw];
  int off = lane * 2;
  float2 a0 = make_float2(0.f, 0.f), a1 = make_float2(0.f, 0.f);
  int i = s;
  for (; i + 1 < e; i += 2){
    int c0 = col[i], c1 = col[i + 1];
    float2 v0 = *(const float2*)(sup + (size_t)c0 * 128 + off);
    float2 v1 = *(const float2*)(sup + (size_t)c1 * 128 + off);
    a0.x += v0.x; a0.y += v0.y;
    a1.x += v1.x; a1.y += v1.y;
  }
  if (i < e){
    int c0 = col[i];
    float2 v0 = *(const float2*)(sup + (size_t)c0 * 128 + off);
    a0.x += v0.x; a0.y += v0.y;
  }
  float v0 = (a0.x + a1.x) * ir, v1 = (a0.y + a1.y) * ir;
  float ss = v0 * v0 + v1 * v1;
  #pragma unroll
  for (int o = 32; o > 0; o >>= 1) ss += __shfl_xor(ss, o);
  float scale = 1.0f / fmaxf(sqrtf(ss), 1e-12f);
  out[(size_t)gw * 128 + off]     = v0 * scale;
  out[(size_t)gw * 128 + off + 1] = v1 * scale;
}

// ---------------- launch ----------------

extern "C" void kernel_launch(void* const* d_in, const int* in_sizes, int n_in,
                              void* d_out, int out_size, void* d_ws, size_t ws_size,
                              hipStream_t stream){
  const float* x  = (const float*)d_in[0];
  const float* W1 = (const float*)d_in[1];
  const float* b1 = (const float*)d_in[2];
  const float* W2 = (const float*)d_in[3];
  const float* b2 = (const float*)d_in[4];
  const float* W3 = (const float*)d_in[5];
  const float* b3 = (const float*)d_in[6];
  const int* edges = (const int*)d_in[7];
  int N = in_sizes[0] / 128;
  int E = in_sizes[7] / 2;

  char* w = (char*)d_ws;
  size_t off = 0;
  auto alloc = [&](size_t bytes)->char*{
    char* p = w + off;
    off = (off + bytes + 255) & ~(size_t)255;
    return p;
  };
  int*   deg     = (int*)  alloc((size_t)N * 4);
  float* inv     = (float*)alloc((size_t)N * 4);
  int*   row_ptr = (int*)  alloc(((size_t)N + 1) * 4);
  int*   cursor  = (int*)  alloc((size_t)N * 4);
  int*   colidx  = (int*)  alloc((size_t)E * 4);
  ushort_t* wt1h = (ushort_t*)alloc((size_t)128 * 256 * 2);
  ushort_t* wt1l = (ushort_t*)alloc((size_t)128 * 256 * 2);
  ushort_t* wt2h = (ushort_t*)alloc((size_t)256 * 256 * 2);
  ushort_t* wt2l = (ushort_t*)alloc((size_t)256 * 256 * 2);
  ushort_t* wt3h = (ushort_t*)alloc((size_t)256 * 128 * 2);
  ushort_t* wt3l = (ushort_t*)alloc((size_t)256 * 128 * 2);
  char* slabA = alloc((size_t)N * 512 * 2);   // 51.2 MB
  char* slabB = alloc((size_t)N * 512 * 2);   // 51.2 MB

  ushort_t* t_pair   = (ushort_t*)slabB;  // [N][256]
  ushort_t* h1_pair  = (ushort_t*)slabA;  // [N][512]
  float*    support2 = (float*)slabB;     // [N][256]
  ushort_t* h2_pair  = (ushort_t*)slabA;  // [N][512]
  float*    support3 = (float*)slabB;     // [N][128]

  hipMemsetAsync(deg, 0, (size_t)N * 4, stream);
  int gE = (E + 255) / 256;
  deg_kernel<<<gE, 256, 0, stream>>>(edges, deg, E);
  scan_kernel<<<1, 1024, 0, stream>>>(deg, row_ptr, cursor, inv, N);
  scatter_kernel<<<gE, 256, 0, stream>>>(edges, cursor, colidx, E);
  sortrows_kernel<<<(N * 64 + 255) / 256, 256, 0, stream>>>(row_ptr, colidx, N);

  wprep_kernel<<<(128*256 + 255)/256, 256, 0, stream>>>(W1, wt1h, wt1l, 128, 256);
  wprep_kernel<<<(256*256 + 255)/256, 256, 0, stream>>>(W2, wt2h, wt2l, 256, 256);
  wprep_kernel<<<(256*128 + 255)/256, 256, 0, stream>>>(W3, wt3h, wt3l, 256, 128);

  int gm = (N + 127) / 128;
  dim3 g12(gm, 2);
  dim3 g3 (gm, 1);
  int gS = (N * 64 + 255) / 256;

  // layer 1 (reordered): t = A_hat x ; h1 = leaky(t@W1 + mask*b1)  [bf16 pair out]
  spmm128_pair_kernel<<<gS, 256, 0, stream>>>(x, row_ptr, colidx, inv, t_pair, N);
  gemm_mfma_kernel<true><<<g12, 256, 0, stream>>>(t_pair, wt1h, wt1l, b1, inv,
                                                  nullptr, h1_pair, N, 128, 256);
  // layer 2: support2 = h1@W2 + b2 ; h2 = leaky(A_hat support2) [bf16 pair out]
  gemm_mfma_kernel<false><<<g12, 256, 0, stream>>>(h1_pair, wt2h, wt2l, b2, nullptr,
                                                   support2, nullptr, N, 256, 256);
  spmm256_leaky_pair_kernel<<<gS, 256, 0, stream>>>(support2, row_ptr, colidx, inv, h2_pair, N);
  // layer 3: support3 = h2@W3 + b3 ; out = normalize(A_hat support3)
  gemm_mfma_kernel<false><<<g3, 256, 0, stream>>>(h2_pair, wt3h, wt3l, b3, nullptr,
                                                  support3, nullptr, N, 256, 128);
  spmm_norm_kernel<<<gS, 256, 0, stream>>>(support3, row_ptr, colidx, inv, (float*)d_out, N);
}

// Round 5
// 522.083 us; speedup vs baseline: 1.5892x; 1.0677x over previous
//
#include <hip/hip_runtime.h>

#define NEG_SLOPE 0.2f

typedef __attribute__((ext_vector_type(8))) short short8;
typedef __attribute__((ext_vector_type(4))) float floatx4;
typedef unsigned short ushort_t;

static __device__ __forceinline__ float leaky(float x){ return x > 0.f ? x : NEG_SLOPE * x; }

static __device__ __forceinline__ unsigned short bf16_rne(float x){
  unsigned u = __float_as_uint(x);
  unsigned r = (u + 0x7fffu + ((u >> 16) & 1u)) >> 16;
  return (unsigned short)r;
}
static __device__ __forceinline__ float bf16_to_f(unsigned short h){
  return __uint_as_float(((unsigned)h) << 16);
}

// ---------------- CSR build ----------------

__global__ void deg_kernel(const int* __restrict__ edges, int* __restrict__ deg, int E){
  int i = blockIdx.x * 256 + threadIdx.x;
  if (i < E) atomicAdd(&deg[edges[2*i + 1]], 1);
}

__global__ __launch_bounds__(1024) void scan_kernel(const int* __restrict__ deg,
    int* __restrict__ row_ptr, int* __restrict__ cursor, float* __restrict__ inv, int n){
  __shared__ int stot[16];
  __shared__ int sCarry;
  int t = threadIdx.x;
  int lane = t & 63, wid = t >> 6;
  if (t == 0) sCarry = 0;
  __syncthreads();
  for (int base = 0; base < n; base += 1024){
    int i = base + t;
    int v = (i < n) ? deg[i] : 0;
    int sc = v;
    #pragma unroll
    for (int off = 1; off < 64; off <<= 1){
      int x = __shfl_up(sc, off);
      if (lane >= off) sc += x;
    }
    if (lane == 63) stot[wid] = sc;
    __syncthreads();
    if (wid == 0){
      int tv = (lane < 16) ? stot[lane] : 0;
      #pragma unroll
      for (int off = 1; off < 16; off <<= 1){
        int x = __shfl_up(tv, off);
        if (lane >= off) tv += x;
      }
      if (lane < 16) stot[lane] = tv;
    }
    __syncthreads();
    int c = sCarry;
    int wbase = (wid > 0) ? stot[wid - 1] : 0;
    int excl = c + wbase + (sc - v);
    if (i < n){
      row_ptr[i] = excl;
      cursor[i]  = excl;
      inv[i] = (v > 0) ? 1.0f / (float)v : 0.0f;
    }
    int total = stot[15];
    __syncthreads();
    if (t == 0) sCarry = c + total;
    __syncthreads();
  }
  if (t == 0) row_ptr[n] = sCarry;
}

__global__ void scatter_kernel(const int* __restrict__ edges, int* __restrict__ cursor,
                               int* __restrict__ col, int E){
  int i = blockIdx.x * 256 + threadIdx.x;
  if (i < E){
    int s = edges[2*i], d = edges[2*i + 1];
    int p = atomicAdd(&cursor[d], 1);
    col[p] = s;
  }
}

// Deterministic col order per row (harness re-validates after replays; f32 sum
// order must be call-invariant). Wave-bitonic sort, all in registers.
__global__ __launch_bounds__(256) void sortrows_kernel(const int* __restrict__ row_ptr,
                                                       int* __restrict__ col, int n){
  int gw = (blockIdx.x * 256 + threadIdx.x) >> 6;
  int lane = threadIdx.x & 63;
  if (gw >= n) return;
  int s = row_ptr[gw], e = row_ptr[gw + 1];
  int len = e - s;
  if (len <= 1) return;
  if (len <= 64){
    int v = (lane < len) ? col[s + lane] : 0x7fffffff;
    #pragma unroll
    for (int k = 2; k <= 64; k <<= 1){
      #pragma unroll
      for (int j = k >> 1; j > 0; j >>= 1){
        int o = __shfl_xor(v, j);
        bool dirUp = ((lane & k) == 0);
        bool takeMin = (((lane & j) == 0) == dirUp);
        v = takeMin ? min(v, o) : max(v, o);
      }
    }
    if (lane < len) col[s + lane] = v;
  } else if (lane == 0){
    for (int i = s + 1; i < e; ++i){
      int v = col[i];
      int j = i - 1;
      while (j >= s && col[j] > v){ col[j + 1] = col[j]; --j; }
      col[j + 1] = v;
    }
  }
}

// ---------------- W prep: transpose + split into bf16 hi/lo planes ----------------

__global__ void wprep_kernel(const float* __restrict__ W, ushort_t* __restrict__ hi,
                             ushort_t* __restrict__ lo, int K, int N){
  int i = blockIdx.x * 256 + threadIdx.x;
  if (i >= K * N) return;
  int k = i / N, n = i - k * N;
  float a = W[i];
  unsigned short h = bf16_rne(a);
  float r = a - bf16_to_f(h);
  hi[(size_t)n * K + k] = h;
  lo[(size_t)n * K + k] = bf16_rne(r);
}

// ---------------- MFMA GEMM ----------------
// A: [M][2K] ushort pair rows (hi[0..K) | lo[0..K)) -- preconverted by producer.
// Split-bf16 3-term: AhBh + AlBh + AhBl, f32 accum.
// 128x128 tile, 4 waves 2x2, BK=32. LDS rows 128B, XOR-swizzle (row&7)<<4.
// L1 mode: C -> bf16 pair [M][2N], leaky, bias masked by (inv>0).
// else:    C -> f32 [M][N], plain bias.

template<bool L1>
__global__ __launch_bounds__(256) void gemm_mfma_kernel(
    const ushort_t* __restrict__ A,
    const ushort_t* __restrict__ Bt_hi, const ushort_t* __restrict__ Bt_lo,
    const float* __restrict__ bias, const float* __restrict__ invv,
    float* __restrict__ Cf, ushort_t* __restrict__ Cp,
    int M, int K, int N){
  __shared__ ushort_t sA[128 * 64];
  __shared__ ushort_t sB[128 * 64];
  const int tid  = threadIdx.x;
  const int lane = tid & 63;
  const int wid  = tid >> 6;
  const int wrow = wid >> 1;
  const int wcol = wid & 1;
  const int br = blockIdx.x * 128;
  const int bc = blockIdx.y * 128;

  floatx4 acc[4][4];
  #pragma unroll
  for (int i = 0; i < 4; i++)
    #pragma unroll
    for (int j = 0; j < 4; j++) acc[i][j] = (floatx4){0.f, 0.f, 0.f, 0.f};

  const int arow = tid >> 1;
  const int asel = tid & 1;
  char* pa = (char*)sA;
  char* pb = (char*)sB;
  const int g16 = (lane >> 4) << 4;

  for (int k0 = 0; k0 < K; k0 += 32){
    // ---- stage A: preconverted pair rows, no VALU conversion ----
    {
      int grow = br + arow;
      short8 hv0, hv1, lv0, lv1;
      if (grow < M){
        const ushort_t* ap = A + (size_t)grow * (2 * K) + k0 + asel * 16;
        hv0 = *(const short8*)(ap);
        hv1 = *(const short8*)(ap + 8);
        lv0 = *(const short8*)(ap + K);
        lv1 = *(const short8*)(ap + K + 8);
      } else {
        hv0 = hv1 = lv0 = lv1 = (short8){0,0,0,0,0,0,0,0};
      }
      unsigned rb  = arow * 128;
      unsigned swz = (arow & 7) << 4;
      unsigned o   = asel * 32;
      *(short8*)(pa + (rb + ((o +  0) ^ swz))) = hv0;
      *(short8*)(pa + (rb + ((o + 16) ^ swz))) = hv1;
      *(short8*)(pa + (rb + ((64 + o +  0) ^ swz))) = lv0;
      *(short8*)(pa + (rb + ((64 + o + 16) ^ swz))) = lv1;
    }
    // ---- stage B ----
    {
      int colb = tid >> 1;
      const ushort_t* src = (asel ? Bt_lo : Bt_hi) + (size_t)(bc + colb) * K + k0;
      short8 v0 = *(const short8*)(src + 0);
      short8 v1 = *(const short8*)(src + 8);
      short8 v2 = *(const short8*)(src + 16);
      short8 v3 = *(const short8*)(src + 24);
      unsigned rb  = colb * 128;
      unsigned swz = (colb & 7) << 4;
      unsigned o   = asel * 64;
      *(short8*)(pb + (rb + ((o +  0) ^ swz))) = v0;
      *(short8*)(pb + (rb + ((o + 16) ^ swz))) = v1;
      *(short8*)(pb + (rb + ((o + 32) ^ swz))) = v2;
      *(short8*)(pb + (rb + ((o + 48) ^ swz))) = v3;
    }
    __syncthreads();
    short8 bh[4], bl[4];
    #pragma unroll
    for (int nf = 0; nf < 4; nf++){
      int coll = wcol * 64 + nf * 16 + (lane & 15);
      unsigned sw = (coll & 7) << 4;
      const char* pr = pb + coll * 128;
      bh[nf] = *(const short8*)(pr + ((g16) ^ sw));
      bl[nf] = *(const short8*)(pr + ((64 + g16) ^ sw));
    }
    #pragma unroll
    for (int mf = 0; mf < 4; mf++){
      int rowl = wrow * 64 + mf * 16 + (lane & 15);
      unsigned sw = (rowl & 7) << 4;
      const char* pr = pa + rowl * 128;
      short8 ah = *(const short8*)(pr + ((g16) ^ sw));
      short8 al = *(const short8*)(pr + ((64 + g16) ^ sw));
      #pragma unroll
      for (int nf = 0; nf < 4; nf++){
        acc[mf][nf] = __builtin_amdgcn_mfma_f32_16x16x32_bf16(ah, bh[nf], acc[mf][nf], 0, 0, 0);
        acc[mf][nf] = __builtin_amdgcn_mfma_f32_16x16x32_bf16(al, bh[nf], acc[mf][nf], 0, 0, 0);
        acc[mf][nf] = __builtin_amdgcn_mfma_f32_16x16x32_bf16(ah, bl[nf], acc[mf][nf], 0, 0, 0);
      }
    }
    __syncthreads();
  }

  const int r0 = br + wrow * 64;
  const int c0 = bc + wcol * 64;
  #pragma unroll
  for (int nf = 0; nf < 4; nf++){
    int col = c0 + nf * 16 + (lane & 15);
    float bv = bias[col];
    #pragma unroll
    for (int mf = 0; mf < 4; mf++){
      int rbase = r0 + mf * 16 + ((lane >> 4) << 2);
      #pragma unroll
      for (int j = 0; j < 4; j++){
        int r = rbase + j;
        if (r >= M) continue;
        float v;
        if (L1){
          float m = (invv[r] > 0.f) ? 1.f : 0.f;
          v = leaky(acc[mf][nf][j] + m * bv);
          unsigned short h = bf16_rne(v);
          unsigned short l = bf16_rne(v - bf16_to_f(h));
          Cp[(size_t)r * (2 * N) + col]     = h;
          Cp[(size_t)r * (2 * N) + N + col] = l;
        } else {
          v = acc[mf][nf][j] + bv;
          Cf[(size_t)r * N + col] = v;
        }
      }
    }
  }
}

// ---------------- SpMM kernels (CSR gather) ----------------

// x (f32 [n][128]) -> t pair (ushort [n][256]); t = inv * sum x[src]
// 2 rows per wave: 32 lanes/row, float4 (16B)/lane, unroll-4.
__global__ __launch_bounds__(256) void spmm128_pair_kernel(const float* __restrict__ x,
    const int* __restrict__ row_ptr, const int* __restrict__ col,
    const float* __restrict__ inv, ushort_t* __restrict__ out, int n){
  int gw = (blockIdx.x * 256 + threadIdx.x) >> 5;   // half-wave id = row
  int lane = threadIdx.x & 31;
  if (gw >= n) return;
  int s = row_ptr[gw], e = row_ptr[gw + 1];
  float ir = inv[gw];
  int off = lane * 4;
  float4 a0 = make_float4(0.f,0.f,0.f,0.f), a1 = make_float4(0.f,0.f,0.f,0.f);
  float4 a2 = make_float4(0.f,0.f,0.f,0.f), a3 = make_float4(0.f,0.f,0.f,0.f);
  int i = s;
  for (; i + 3 < e; i += 4){
    int c0 = col[i], c1 = col[i+1], c2 = col[i+2], c3 = col[i+3];
    float4 v0 = *(const float4*)(x + (size_t)c0 * 128 + off);
    float4 v1 = *(const float4*)(x + (size_t)c1 * 128 + off);
    float4 v2 = *(const float4*)(x + (size_t)c2 * 128 + off);
    float4 v3 = *(const float4*)(x + (size_t)c3 * 128 + off);
    a0.x += v0.x; a0.y += v0.y; a0.z += v0.z; a0.w += v0.w;
    a1.x += v1.x; a1.y += v1.y; a1.z += v1.z; a1.w += v1.w;
    a2.x += v2.x; a2.y += v2.y; a2.z += v2.z; a2.w += v2.w;
    a3.x += v3.x; a3.y += v3.y; a3.z += v3.z; a3.w += v3.w;
  }
  for (; i < e; ++i){
    int c0 = col[i];
    float4 v0 = *(const float4*)(x + (size_t)c0 * 128 + off);
    a0.x += v0.x; a0.y += v0.y; a0.z += v0.z; a0.w += v0.w;
  }
  float f[4];
  f[0] = ((a0.x + a1.x) + (a2.x + a3.x)) * ir;
  f[1] = ((a0.y + a1.y) + (a2.y + a3.y)) * ir;
  f[2] = ((a0.z + a1.z) + (a2.z + a3.z)) * ir;
  f[3] = ((a0.w + a1.w) + (a2.w + a3.w)) * ir;
  ushort4 hv, lv;
  ushort_t h;
  h = bf16_rne(f[0]); hv.x = h; lv.x = bf16_rne(f[0] - bf16_to_f(h));
  h = bf16_rne(f[1]); hv.y = h; lv.y = bf16_rne(f[1] - bf16_to_f(h));
  h = bf16_rne(f[2]); hv.z = h; lv.z = bf16_rne(f[2] - bf16_to_f(h));
  h = bf16_rne(f[3]); hv.w = h; lv.w = bf16_rne(f[3] - bf16_to_f(h));
  *(ushort4*)(out + (size_t)gw * 256 + off)       = hv;
  *(ushort4*)(out + (size_t)gw * 256 + 128 + off) = lv;
}

// support (f32 [n][256]) -> h pair (ushort [n][512]); h = leaky(inv * sum)
// 1 row per wave: 64 lanes, float4/lane, unroll-4.
__global__ __launch_bounds__(256) void spmm256_leaky_pair_kernel(const float* __restrict__ sup,
    const int* __restrict__ row_ptr, const int* __restrict__ col,
    const float* __restrict__ inv, ushort_t* __restrict__ out, int n){
  int gw = (blockIdx.x * 256 + threadIdx.x) >> 6;
  int lane = threadIdx.x & 63;
  if (gw >= n) return;
  int s = row_ptr[gw], e = row_ptr[gw + 1];
  float ir = inv[gw];
  int off = lane * 4;
  float4 a0 = make_float4(0.f,0.f,0.f,0.f), a1 = make_float4(0.f,0.f,0.f,0.f);
  float4 a2 = make_float4(0.f,0.f,0.f,0.f), a3 = make_float4(0.f,0.f,0.f,0.f);
  int i = s;
  for (; i + 3 < e; i += 4){
    int c0 = col[i], c1 = col[i+1], c2 = col[i+2], c3 = col[i+3];
    float4 v0 = *(const float4*)(sup + (size_t)c0 * 256 + off);
    float4 v1 = *(const float4*)(sup + (size_t)c1 * 256 + off);
    float4 v2 = *(const float4*)(sup + (size_t)c2 * 256 + off);
    float4 v3 = *(const float4*)(sup + (size_t)c3 * 256 + off);
    a0.x += v0.x; a0.y += v0.y; a0.z += v0.z; a0.w += v0.w;
    a1.x += v1.x; a1.y += v1.y; a1.z += v1.z; a1.w += v1.w;
    a2.x += v2.x; a2.y += v2.y; a2.z += v2.z; a2.w += v2.w;
    a3.x += v3.x; a3.y += v3.y; a3.z += v3.z; a3.w += v3.w;
  }
  for (; i < e; ++i){
    int c0 = col[i];
    float4 v0 = *(const float4*)(sup + (size_t)c0 * 256 + off);
    a0.x += v0.x; a0.y += v0.y; a0.z += v0.z; a0.w += v0.w;
  }
  float f[4];
  f[0] = leaky(((a0.x + a1.x) + (a2.x + a3.x)) * ir);
  f[1] = leaky(((a0.y + a1.y) + (a2.y + a3.y)) * ir);
  f[2] = leaky(((a0.z + a1.z) + (a2.z + a3.z)) * ir);
  f[3] = leaky(((a0.w + a1.w) + (a2.w + a3.w)) * ir);
  ushort4 hv, lv;
  ushort_t h;
  h = bf16_rne(f[0]); hv.x = h; lv.x = bf16_rne(f[0] - bf16_to_f(h));
  h = bf16_rne(f[1]); hv.y = h; lv.y = bf16_rne(f[1] - bf16_to_f(h));
  h = bf16_rne(f[2]); hv.z = h; lv.z = bf16_rne(f[2] - bf16_to_f(h));
  h = bf16_rne(f[3]); hv.w = h; lv.w = bf16_rne(f[3] - bf16_to_f(h));
  *(ushort4*)(out + (size_t)gw * 512 + off)       = hv;
  *(ushort4*)(out + (size_t)gw * 512 + 256 + off) = lv;
}

// support (f32 [n][128]) -> out f32 [n][128]; inv-scale + L2 row-normalize
// 2 rows per wave: 32 lanes/row, float4/lane, unroll-4.
__global__ __launch_bounds__(256) void spmm_norm_kernel(const float* __restrict__ sup,
    const int* __restrict__ row_ptr, const int* __restrict__ col,
    const float* __restrict__ inv, float* __restrict__ out, int n){
  int gw = (blockIdx.x * 256 + threadIdx.x) >> 5;   // half-wave id = row
  int lane = threadIdx.x & 31;
  if (gw >= n) return;
  int s = row_ptr[gw], e = row_ptr[gw + 1];
  float ir = inv[gw];
  int off = lane * 4;
  float4 a0 = make_float4(0.f,0.f,0.f,0.f), a1 = make_float4(0.f,0.f,0.f,0.f);
  float4 a2 = make_float4(0.f,0.f,0.f,0.f), a3 = make_float4(0.f,0.f,0.f,0.f);
  int i = s;
  for (; i + 3 < e; i += 4){
    int c0 = col[i], c1 = col[i+1], c2 = col[i+2], c3 = col[i+3];
    float4 v0 = *(const float4*)(sup + (size_t)c0 * 128 + off);
    float4 v1 = *(const float4*)(sup + (size_t)c1 * 128 + off);
    float4 v2 = *(const float4*)(sup + (size_t)c2 * 128 + off);
    float4 v3 = *(const float4*)(sup + (size_t)c3 * 128 + off);
    a0.x += v0.x; a0.y += v0.y; a0.z += v0.z; a0.w += v0.w;
    a1.x += v1.x; a1.y += v1.y; a1.z += v1.z; a1.w += v1.w;
    a2.x += v2.x; a2.y += v2.y; a2.z += v2.z; a2.w += v2.w;
    a3.x += v3.x; a3.y += v3.y; a3.z += v3.z; a3.w += v3.w;
  }
  for (; i < e; ++i){
    int c0 = col[i];
    float4 v0 = *(const float4*)(sup + (size_t)c0 * 128 + off);
    a0.x += v0.x; a0.y += v0.y; a0.z += v0.z; a0.w += v0.w;
  }
  float v0 = ((a0.x + a1.x) + (a2.x + a3.x)) * ir;
  float v1 = ((a0.y + a1.y) + (a2.y + a3.y)) * ir;
  float v2 = ((a0.z + a1.z) + (a2.z + a3.z)) * ir;
  float v3 = ((a0.w + a1.w) + (a2.w + a3.w)) * ir;
  float ss = v0*v0 + v1*v1 + v2*v2 + v3*v3;
  #pragma unroll
  for (int o = 16; o > 0; o >>= 1) ss += __shfl_xor(ss, o);   // stays within 32-lane half
  float scale = 1.0f / fmaxf(sqrtf(ss), 1e-12f);
  float4 ov;
  ov.x = v0 * scale; ov.y = v1 * scale; ov.z = v2 * scale; ov.w = v3 * scale;
  *(float4*)(out + (size_t)gw * 128 + off) = ov;
}

// ---------------- launch ----------------

extern "C" void kernel_launch(void* const* d_in, const int* in_sizes, int n_in,
                              void* d_out, int out_size, void* d_ws, size_t ws_size,
                              hipStream_t stream){
  const float* x  = (const float*)d_in[0];
  const float* W1 = (const float*)d_in[1];
  const float* b1 = (const float*)d_in[2];
  const float* W2 = (const float*)d_in[3];
  const float* b2 = (const float*)d_in[4];
  const float* W3 = (const float*)d_in[5];
  const float* b3 = (const float*)d_in[6];
  const int* edges = (const int*)d_in[7];
  int N = in_sizes[0] / 128;
  int E = in_sizes[7] / 2;

  char* w = (char*)d_ws;
  size_t off = 0;
  auto alloc = [&](size_t bytes)->char*{
    char* p = w + off;
    off = (off + bytes + 255) & ~(size_t)255;
    return p;
  };
  int*   deg     = (int*)  alloc((size_t)N * 4);
  float* inv     = (float*)alloc((size_t)N * 4);
  int*   row_ptr = (int*)  alloc(((size_t)N + 1) * 4);
  int*   cursor  = (int*)  alloc((size_t)N * 4);
  int*   colidx  = (int*)  alloc((size_t)E * 4);
  ushort_t* wt1h = (ushort_t*)alloc((size_t)128 * 256 * 2);
  ushort_t* wt1l = (ushort_t*)alloc((size_t)128 * 256 * 2);
  ushort_t* wt2h = (ushort_t*)alloc((size_t)256 * 256 * 2);
  ushort_t* wt2l = (ushort_t*)alloc((size_t)256 * 256 * 2);
  ushort_t* wt3h = (ushort_t*)alloc((size_t)256 * 128 * 2);
  ushort_t* wt3l = (ushort_t*)alloc((size_t)256 * 128 * 2);
  char* slabA = alloc((size_t)N * 512 * 2);   // 51.2 MB
  char* slabB = alloc((size_t)N * 512 * 2);   // 51.2 MB

  ushort_t* t_pair   = (ushort_t*)slabB;  // [N][256]
  ushort_t* h1_pair  = (ushort_t*)slabA;  // [N][512]
  float*    support2 = (float*)slabB;     // [N][256]
  ushort_t* h2_pair  = (ushort_t*)slabA;  // [N][512]
  float*    support3 = (float*)slabB;     // [N][128]

  hipMemsetAsync(deg, 0, (size_t)N * 4, stream);
  int gE = (E + 255) / 256;
  deg_kernel<<<gE, 256, 0, stream>>>(edges, deg, E);
  scan_kernel<<<1, 1024, 0, stream>>>(deg, row_ptr, cursor, inv, N);
  scatter_kernel<<<gE, 256, 0, stream>>>(edges, cursor, colidx, E);
  sortrows_kernel<<<(N * 64 + 255) / 256, 256, 0, stream>>>(row_ptr, colidx, N);

  wprep_kernel<<<(128*256 + 255)/256, 256, 0, stream>>>(W1, wt1h, wt1l, 128, 256);
  wprep_kernel<<<(256*256 + 255)/256, 256, 0, stream>>>(W2, wt2h, wt2l, 256, 256);
  wprep_kernel<<<(256*128 + 255)/256, 256, 0, stream>>>(W3, wt3h, wt3l, 256, 128);

  int gm = (N + 127) / 128;
  dim3 g12(gm, 2);
  dim3 g3 (gm, 1);
  int gS64 = (N * 64 + 255) / 256;   // 1 row per wave
  int gS32 = (N * 32 + 255) / 256;   // 2 rows per wave

  // layer 1 (reordered): t = A_hat x ; h1 = leaky(t@W1 + mask*b1)  [bf16 pair out]
  spmm128_pair_kernel<<<gS32, 256, 0, stream>>>(x, row_ptr, colidx, inv, t_pair, N);
  gemm_mfma_kernel<true><<<g12, 256, 0, stream>>>(t_pair, wt1h, wt1l, b1, inv,
                                                  nullptr, h1_pair, N, 128, 256);
  // layer 2: support2 = h1@W2 + b2 ; h2 = leaky(A_hat support2) [bf16 pair out]
  gemm_mfma_kernel<false><<<g12, 256, 0, stream>>>(h1_pair, wt2h, wt2l, b2, nullptr,
                                                   support2, nullptr, N, 256, 256);
  spmm256_leaky_pair_kernel<<<gS64, 256, 0, stream>>>(support2, row_ptr, colidx, inv, h2_pair, N);
  // layer 3: support3 = h2@W3 + b3 ; out = normalize(A_hat support3)
  gemm_mfma_kernel<false><<<g3, 256, 0, stream>>>(h2_pair, wt3h, wt3l, b3, nullptr,
                                                  support3, nullptr, N, 256, 128);
  spmm_norm_kernel<<<gS32, 256, 0, stream>>>(support3, row_ptr, colidx, inv, (float*)d_out, N);
}

// Round 6
// 464.545 us; speedup vs baseline: 1.7861x; 1.1239x over previous
//
#include <hip/hip_runtime.h>

#define NEG_SLOPE 0.2f

typedef __attribute__((ext_vector_type(8))) short short8;
typedef __attribute__((ext_vector_type(4))) float floatx4;
typedef unsigned short ushort_t;

static __device__ __forceinline__ float leaky(float x){ return x > 0.f ? x : NEG_SLOPE * x; }

static __device__ __forceinline__ unsigned short bf16_rne(float x){
  unsigned u = __float_as_uint(x);
  unsigned r = (u + 0x7fffu + ((u >> 16) & 1u)) >> 16;
  return (unsigned short)r;
}
static __device__ __forceinline__ float bf16_to_f(unsigned short h){
  return __uint_as_float(((unsigned)h) << 16);
}

#define GLOAD_LDS16(g, l) \
  __builtin_amdgcn_global_load_lds((const __attribute__((address_space(1))) unsigned*)(g), \
                                   (__attribute__((address_space(3))) unsigned*)(l), 16, 0, 0)

// ---------------- CSR build ----------------

__global__ void deg_kernel(const int* __restrict__ edges, int* __restrict__ deg, int E){
  int i = blockIdx.x * 256 + threadIdx.x;
  if (i < E) atomicAdd(&deg[edges[2*i + 1]], 1);
}

// hierarchical scan: (1) per-block sums
__global__ __launch_bounds__(256) void scan_part_kernel(const int* __restrict__ deg,
                                                        int* __restrict__ partial, int n){
  int i = blockIdx.x * 256 + threadIdx.x;
  int v = (i < n) ? deg[i] : 0;
  #pragma unroll
  for (int o = 32; o > 0; o >>= 1) v += __shfl_xor(v, o);
  __shared__ int ws[4];
  if ((threadIdx.x & 63) == 0) ws[threadIdx.x >> 6] = v;
  __syncthreads();
  if (threadIdx.x == 0) partial[blockIdx.x] = ws[0] + ws[1] + ws[2] + ws[3];
}

// (2) exclusive scan of partials (nb <= 256), single block
__global__ __launch_bounds__(256) void scan_top_kernel(int* __restrict__ partial, int nb){
  int t = threadIdx.x;
  int lane = t & 63, w = t >> 6;
  int v = (t < nb) ? partial[t] : 0;
  int sc = v;
  #pragma unroll
  for (int o = 1; o < 64; o <<= 1){
    int x = __shfl_up(sc, o);
    if (lane >= o) sc += x;
  }
  __shared__ int wt[4];
  if (lane == 63) wt[w] = sc;
  __syncthreads();
  int base = 0;
  for (int j = 0; j < w; j++) base += wt[j];
  if (t < nb) partial[t] = base + sc - v;
}

// (3) block-local exclusive scan + partial offset -> row_ptr, cursor, inv
__global__ __launch_bounds__(256) void scan_fin_kernel(const int* __restrict__ deg,
    const int* __restrict__ partial, int* __restrict__ row_ptr, int* __restrict__ cursor,
    float* __restrict__ inv, int n){
  int b = blockIdx.x, t = threadIdx.x;
  int i = b * 256 + t;
  int lane = t & 63, w = t >> 6;
  int v = (i < n) ? deg[i] : 0;
  int sc = v;
  #pragma unroll
  for (int o = 1; o < 64; o <<= 1){
    int x = __shfl_up(sc, o);
    if (lane >= o) sc += x;
  }
  __shared__ int wt[4];
  if (lane == 63) wt[w] = sc;
  __syncthreads();
  int base = partial[b];
  for (int j = 0; j < w; j++) base += wt[j];
  int excl = base + sc - v;
  if (i < n){
    row_ptr[i] = excl;
    cursor[i]  = excl;
    inv[i] = (v > 0) ? 1.0f / (float)v : 0.0f;
    if (i == n - 1) row_ptr[n] = excl + v;
  }
}

__global__ void scatter_kernel(const int* __restrict__ edges, int* __restrict__ cursor,
                               int* __restrict__ col, int E){
  int i = blockIdx.x * 256 + threadIdx.x;
  if (i < E){
    int s = edges[2*i], d = edges[2*i + 1];
    int p = atomicAdd(&cursor[d], 1);
    col[p] = s;
  }
}

// Deterministic col order per row (harness re-validates after replays; f32 sum
// order must be call-invariant). Wave-bitonic sort, all in registers.
__global__ __launch_bounds__(256) void sortrows_kernel(const int* __restrict__ row_ptr,
                                                       int* __restrict__ col, int n){
  int gw = (blockIdx.x * 256 + threadIdx.x) >> 6;
  int lane = threadIdx.x & 63;
  if (gw >= n) return;
  int s = row_ptr[gw], e = row_ptr[gw + 1];
  int len = e - s;
  if (len <= 1) return;
  if (len <= 64){
    int v = (lane < len) ? col[s + lane] : 0x7fffffff;
    #pragma unroll
    for (int k = 2; k <= 64; k <<= 1){
      #pragma unroll
      for (int j = k >> 1; j > 0; j >>= 1){
        int o = __shfl_xor(v, j);
        bool dirUp = ((lane & k) == 0);
        bool takeMin = (((lane & j) == 0) == dirUp);
        v = takeMin ? min(v, o) : max(v, o);
      }
    }
    if (lane < len) col[s + lane] = v;
  } else if (lane == 0){
    for (int i = s + 1; i < e; ++i){
      int v = col[i];
      int j = i - 1;
      while (j >= s && col[j] > v){ col[j + 1] = col[j]; --j; }
      col[j + 1] = v;
    }
  }
}

// ---------------- W prep: transpose + split into bf16 hi/lo planes ----------------

__global__ void wprep_kernel(const float* __restrict__ W, ushort_t* __restrict__ hi,
                             ushort_t* __restrict__ lo, int K, int N){
  int i = blockIdx.x * 256 + threadIdx.x;
  if (i >= K * N) return;
  int k = i / N, n = i - k * N;
  float a = W[i];
  unsigned short h = bf16_rne(a);
  float r = a - bf16_to_f(h);
  hi[(size_t)n * K + k] = h;
  lo[(size_t)n * K + k] = bf16_rne(r);
}

// ---------------- MFMA GEMM ----------------
// A: [M][2K] ushort pair rows (hi[0..K) | lo[0..K)) -- preconverted by producer.
// Split-bf16 3-term: AhBh + AlBh + AhBl, f32 accum.
// 128x128 tile, 4 waves 2x2, BK=32.
// LDS tile: 128 rows x 128B. Logical chunk j (0..7) of row r lives at LDS chunk
// j ^ (r&7) (XOR bank swizzle). Staged via global_load_lds with LINEAR LDS dest
// and inverse-swizzled GLOBAL source (rule: swizzle both sides or neither).
// chunks 0..3 = hi plane (32 bf16), chunks 4..7 = lo plane.

template<bool L1>
__global__ __launch_bounds__(256) void gemm_mfma_kernel(
    const ushort_t* __restrict__ A,
    const ushort_t* __restrict__ Bt_hi, const ushort_t* __restrict__ Bt_lo,
    const float* __restrict__ bias, const float* __restrict__ invv,
    float* __restrict__ Cf, ushort_t* __restrict__ Cp,
    int M, int K, int N){
  __shared__ ushort_t sA[128 * 64];   // 16 KB
  __shared__ ushort_t sB[128 * 64];   // 16 KB
  const int tid  = threadIdx.x;
  const int lane = tid & 63;
  const int wid  = tid >> 6;
  const int wrow = wid >> 1;
  const int wcol = wid & 1;
  const int br = blockIdx.x * 128;
  const int bc = blockIdx.y * 128;

  floatx4 acc[4][4];
  #pragma unroll
  for (int i = 0; i < 4; i++)
    #pragma unroll
    for (int j = 0; j < 4; j++) acc[i][j] = (floatx4){0.f, 0.f, 0.f, 0.f};

  char* pa = (char*)sA;
  char* pb = (char*)sB;
  const int g16 = (lane >> 4) << 4;
  const int r_st = tid >> 3;          // row within pass group (0..31)
  const int c_st = tid & 7;           // linear LDS chunk this lane fills

  for (int k0 = 0; k0 < K; k0 += 32){
    // ---- stage A and B via global_load_lds, 4 passes each ----
    #pragma unroll
    for (int q = 0; q < 4; q++){
      int r  = q * 32 + r_st;                 // tile row (A) / tile col (B)
      int sc = c_st ^ (r & 7);                // inverse-swizzled logical chunk
      int hiOff = k0 + sc * 8;                // elements, chunks 0..3 (hi plane)
      int loOff = K + k0 + (sc - 4) * 8;      // elements, chunks 4..7 (lo plane)
      {
        int grow = br + r;
        if (grow < M){
          const ushort_t* src = A + (size_t)grow * (2 * K) + ((sc < 4) ? hiOff : loOff);
          GLOAD_LDS16(src, pa + q * 4096 + wid * 1024);
        }
      }
      {
        int gcol = bc + r;                    // always < N (grid exact)
        const ushort_t* srcB = (sc < 4) ? (Bt_hi + (size_t)gcol * K + k0 + sc * 8)
                                        : (Bt_lo + (size_t)gcol * K + k0 + (sc - 4) * 8);
        GLOAD_LDS16(srcB, pb + q * 4096 + wid * 1024);
      }
    }
    __syncthreads();
    // ---- fragments + MFMA (reads swizzled: chunk j at byte (j*16)^((r&7)<<4)) ----
    short8 bh[4], bl[4];
    #pragma unroll
    for (int nf = 0; nf < 4; nf++){
      int coll = wcol * 64 + nf * 16 + (lane & 15);
      unsigned sw = (coll & 7) << 4;
      const char* pr = pb + coll * 128;
      bh[nf] = *(const short8*)(pr + ((g16) ^ sw));
      bl[nf] = *(const short8*)(pr + ((64 + g16) ^ sw));
    }
    #pragma unroll
    for (int mf = 0; mf < 4; mf++){
      int rowl = wrow * 64 + mf * 16 + (lane & 15);
      unsigned sw = (rowl & 7) << 4;
      const char* pr = pa + rowl * 128;
      short8 ah = *(const short8*)(pr + ((g16) ^ sw));
      short8 al = *(const short8*)(pr + ((64 + g16) ^ sw));
      #pragma unroll
      for (int nf = 0; nf < 4; nf++){
        acc[mf][nf] = __builtin_amdgcn_mfma_f32_16x16x32_bf16(ah, bh[nf], acc[mf][nf], 0, 0, 0);
        acc[mf][nf] = __builtin_amdgcn_mfma_f32_16x16x32_bf16(al, bh[nf], acc[mf][nf], 0, 0, 0);
        acc[mf][nf] = __builtin_amdgcn_mfma_f32_16x16x32_bf16(ah, bl[nf], acc[mf][nf], 0, 0, 0);
      }
    }
    __syncthreads();
  }

  const int r0 = br + wrow * 64;
  const int c0 = bc + wcol * 64;
  #pragma unroll
  for (int nf = 0; nf < 4; nf++){
    int col = c0 + nf * 16 + (lane & 15);
    float bv = bias[col];
    #pragma unroll
    for (int mf = 0; mf < 4; mf++){
      int rbase = r0 + mf * 16 + ((lane >> 4) << 2);
      #pragma unroll
      for (int j = 0; j < 4; j++){
        int r = rbase + j;
        if (r >= M) continue;
        float v;
        if (L1){
          float m = (invv[r] > 0.f) ? 1.f : 0.f;
          v = leaky(acc[mf][nf][j] + m * bv);
          unsigned short h = bf16_rne(v);
          unsigned short l = bf16_rne(v - bf16_to_f(h));
          Cp[(size_t)r * (2 * N) + col]     = h;
          Cp[(size_t)r * (2 * N) + N + col] = l;
        } else {
          v = acc[mf][nf][j] + bv;
          Cf[(size_t)r * N + col] = v;
        }
      }
    }
  }
}

// ---------------- SpMM kernels (CSR gather) ----------------

// x (f32 [n][128]) -> t pair (ushort [n][256]); t = inv * sum x[src]
// 2 rows per wave: 32 lanes/row, float4 (16B)/lane, unroll-4.
__global__ __launch_bounds__(256) void spmm128_pair_kernel(const float* __restrict__ x,
    const int* __restrict__ row_ptr, const int* __restrict__ col,
    const float* __restrict__ inv, ushort_t* __restrict__ out, int n){
  int gw = (blockIdx.x * 256 + threadIdx.x) >> 5;
  int lane = threadIdx.x & 31;
  if (gw >= n) return;
  int s = row_ptr[gw], e = row_ptr[gw + 1];
  float ir = inv[gw];
  int off = lane * 4;
  float4 a0 = make_float4(0.f,0.f,0.f,0.f), a1 = make_float4(0.f,0.f,0.f,0.f);
  float4 a2 = make_float4(0.f,0.f,0.f,0.f), a3 = make_float4(0.f,0.f,0.f,0.f);
  int i = s;
  for (; i + 3 < e; i += 4){
    int c0 = col[i], c1 = col[i+1], c2 = col[i+2], c3 = col[i+3];
    float4 v0 = *(const float4*)(x + (size_t)c0 * 128 + off);
    float4 v1 = *(const float4*)(x + (size_t)c1 * 128 + off);
    float4 v2 = *(const float4*)(x + (size_t)c2 * 128 + off);
    float4 v3 = *(const float4*)(x + (size_t)c3 * 128 + off);
    a0.x += v0.x; a0.y += v0.y; a0.z += v0.z; a0.w += v0.w;
    a1.x += v1.x; a1.y += v1.y; a1.z += v1.z; a1.w += v1.w;
    a2.x += v2.x; a2.y += v2.y; a2.z += v2.z; a2.w += v2.w;
    a3.x += v3.x; a3.y += v3.y; a3.z += v3.z; a3.w += v3.w;
  }
  for (; i < e; ++i){
    int c0 = col[i];
    float4 v0 = *(const float4*)(x + (size_t)c0 * 128 + off);
    a0.x += v0.x; a0.y += v0.y; a0.z += v0.z; a0.w += v0.w;
  }
  float f[4];
  f[0] = ((a0.x + a1.x) + (a2.x + a3.x)) * ir;
  f[1] = ((a0.y + a1.y) + (a2.y + a3.y)) * ir;
  f[2] = ((a0.z + a1.z) + (a2.z + a3.z)) * ir;
  f[3] = ((a0.w + a1.w) + (a2.w + a3.w)) * ir;
  ushort4 hv, lv;
  ushort_t h;
  h = bf16_rne(f[0]); hv.x = h; lv.x = bf16_rne(f[0] - bf16_to_f(h));
  h = bf16_rne(f[1]); hv.y = h; lv.y = bf16_rne(f[1] - bf16_to_f(h));
  h = bf16_rne(f[2]); hv.z = h; lv.z = bf16_rne(f[2] - bf16_to_f(h));
  h = bf16_rne(f[3]); hv.w = h; lv.w = bf16_rne(f[3] - bf16_to_f(h));
  *(ushort4*)(out + (size_t)gw * 256 + off)       = hv;
  *(ushort4*)(out + (size_t)gw * 256 + 128 + off) = lv;
}

// support (f32 [n][256]) -> h pair (ushort [n][512]); h = leaky(inv * sum)
__global__ __launch_bounds__(256) void spmm256_leaky_pair_kernel(const float* __restrict__ sup,
    const int* __restrict__ row_ptr, const int* __restrict__ col,
    const float* __restrict__ inv, ushort_t* __restrict__ out, int n){
  int gw = (blockIdx.x * 256 + threadIdx.x) >> 6;
  int lane = threadIdx.x & 63;
  if (gw >= n) return;
  int s = row_ptr[gw], e = row_ptr[gw + 1];
  float ir = inv[gw];
  int off = lane * 4;
  float4 a0 = make_float4(0.f,0.f,0.f,0.f), a1 = make_float4(0.f,0.f,0.f,0.f);
  float4 a2 = make_float4(0.f,0.f,0.f,0.f), a3 = make_float4(0.f,0.f,0.f,0.f);
  int i = s;
  for (; i + 3 < e; i += 4){
    int c0 = col[i], c1 = col[i+1], c2 = col[i+2], c3 = col[i+3];
    float4 v0 = *(const float4*)(sup + (size_t)c0 * 256 + off);
    float4 v1 = *(const float4*)(sup + (size_t)c1 * 256 + off);
    float4 v2 = *(const float4*)(sup + (size_t)c2 * 256 + off);
    float4 v3 = *(const float4*)(sup + (size_t)c3 * 256 + off);
    a0.x += v0.x; a0.y += v0.y; a0.z += v0.z; a0.w += v0.w;
    a1.x += v1.x; a1.y += v1.y; a1.z += v1.z; a1.w += v1.w;
    a2.x += v2.x; a2.y += v2.y; a2.z += v2.z; a2.w += v2.w;
    a3.x += v3.x; a3.y += v3.y; a3.z += v3.z; a3.w += v3.w;
  }
  for (; i < e; ++i){
    int c0 = col[i];
    float4 v0 = *(const float4*)(sup + (size_t)c0 * 256 + off);
    a0.x += v0.x; a0.y += v0.y; a0.z += v0.z; a0.w += v0.w;
  }
  float f[4];
  f[0] = leaky(((a0.x + a1.x) + (a2.x + a3.x)) * ir);
  f[1] = leaky(((a0.y + a1.y) + (a2.y + a3.y)) * ir);
  f[2] = leaky(((a0.z + a1.z) + (a2.z + a3.z)) * ir);
  f[3] = leaky(((a0.w + a1.w) + (a2.w + a3.w)) * ir);
  ushort4 hv, lv;
  ushort_t h;
  h = bf16_rne(f[0]); hv.x = h; lv.x = bf16_rne(f[0] - bf16_to_f(h));
  h = bf16_rne(f[1]); hv.y = h; lv.y = bf16_rne(f[1] - bf16_to_f(h));
  h = bf16_rne(f[2]); hv.z = h; lv.z = bf16_rne(f[2] - bf16_to_f(h));
  h = bf16_rne(f[3]); hv.w = h; lv.w = bf16_rne(f[3] - bf16_to_f(h));
  *(ushort4*)(out + (size_t)gw * 512 + off)       = hv;
  *(ushort4*)(out + (size_t)gw * 512 + 256 + off) = lv;
}

// support (f32 [n][128]) -> out f32 [n][128]; inv-scale + L2 row-normalize
__global__ __launch_bounds__(256) void spmm_norm_kernel(const float* __restrict__ sup,
    const int* __restrict__ row_ptr, const int* __restrict__ col,
    const float* __restrict__ inv, float* __restrict__ out, int n){
  int gw = (blockIdx.x * 256 + threadIdx.x) >> 5;
  int lane = threadIdx.x & 31;
  if (gw >= n) return;
  int s = row_ptr[gw], e = row_ptr[gw + 1];
  float ir = inv[gw];
  int off = lane * 4;
  float4 a0 = make_float4(0.f,0.f,0.f,0.f), a1 = make_float4(0.f,0.f,0.f,0.f);
  float4 a2 = make_float4(0.f,0.f,0.f,0.f), a3 = make_float4(0.f,0.f,0.f,0.f);
  int i = s;
  for (; i + 3 < e; i += 4){
    int c0 = col[i], c1 = col[i+1], c2 = col[i+2], c3 = col[i+3];
    float4 v0 = *(const float4*)(sup + (size_t)c0 * 128 + off);
    float4 v1 = *(const float4*)(sup + (size_t)c1 * 128 + off);
    float4 v2 = *(const float4*)(sup + (size_t)c2 * 128 + off);
    float4 v3 = *(const float4*)(sup + (size_t)c3 * 128 + off);
    a0.x += v0.x; a0.y += v0.y; a0.z += v0.z; a0.w += v0.w;
    a1.x += v1.x; a1.y += v1.y; a1.z += v1.z; a1.w += v1.w;
    a2.x += v2.x; a2.y += v2.y; a2.z += v2.z; a2.w += v2.w;
    a3.x += v3.x; a3.y += v3.y; a3.z += v3.z; a3.w += v3.w;
  }
  for (; i < e; ++i){
    int c0 = col[i];
    float4 v0 = *(const float4*)(sup + (size_t)c0 * 128 + off);
    a0.x += v0.x; a0.y += v0.y; a0.z += v0.z; a0.w += v0.w;
  }
  float v0 = ((a0.x + a1.x) + (a2.x + a3.x)) * ir;
  float v1 = ((a0.y + a1.y) + (a2.y + a3.y)) * ir;
  float v2 = ((a0.z + a1.z) + (a2.z + a3.z)) * ir;
  float v3 = ((a0.w + a1.w) + (a2.w + a3.w)) * ir;
  float ss = v0*v0 + v1*v1 + v2*v2 + v3*v3;
  #pragma unroll
  for (int o = 16; o > 0; o >>= 1) ss += __shfl_xor(ss, o);
  float scale = 1.0f / fmaxf(sqrtf(ss), 1e-12f);
  float4 ov;
  ov.x = v0 * scale; ov.y = v1 * scale; ov.z = v2 * scale; ov.w = v3 * scale;
  *(float4*)(out + (size_t)gw * 128 + off) = ov;
}

// ---------------- launch ----------------

extern "C" void kernel_launch(void* const* d_in, const int* in_sizes, int n_in,
                              void* d_out, int out_size, void* d_ws, size_t ws_size,
                              hipStream_t stream){
  const float* x  = (const float*)d_in[0];
  const float* W1 = (const float*)d_in[1];
  const float* b1 = (const float*)d_in[2];
  const float* W2 = (const float*)d_in[3];
  const float* b2 = (const float*)d_in[4];
  const float* W3 = (const float*)d_in[5];
  const float* b3 = (const float*)d_in[6];
  const int* edges = (const int*)d_in[7];
  int N = in_sizes[0] / 128;
  int E = in_sizes[7] / 2;

  char* w = (char*)d_ws;
  size_t off = 0;
  auto alloc = [&](size_t bytes)->char*{
    char* p = w + off;
    off = (off + bytes + 255) & ~(size_t)255;
    return p;
  };
  int nBlocks = (N + 255) / 256;
  int*   deg     = (int*)  alloc((size_t)N * 4);
  float* inv     = (float*)alloc((size_t)N * 4);
  int*   row_ptr = (int*)  alloc(((size_t)N + 1) * 4);
  int*   cursor  = (int*)  alloc((size_t)N * 4);
  int*   colidx  = (int*)  alloc((size_t)E * 4);
  int*   partial = (int*)  alloc((size_t)nBlocks * 4);
  ushort_t* wt1h = (ushort_t*)alloc((size_t)128 * 256 * 2);
  ushort_t* wt1l = (ushort_t*)alloc((size_t)128 * 256 * 2);
  ushort_t* wt2h = (ushort_t*)alloc((size_t)256 * 256 * 2);
  ushort_t* wt2l = (ushort_t*)alloc((size_t)256 * 256 * 2);
  ushort_t* wt3h = (ushort_t*)alloc((size_t)256 * 128 * 2);
  ushort_t* wt3l = (ushort_t*)alloc((size_t)256 * 128 * 2);
  char* slabA = alloc((size_t)N * 512 * 2);   // 51.2 MB
  char* slabB = alloc((size_t)N * 512 * 2);   // 51.2 MB

  ushort_t* t_pair   = (ushort_t*)slabB;  // [N][256]
  ushort_t* h1_pair  = (ushort_t*)slabA;  // [N][512]
  float*    support2 = (float*)slabB;     // [N][256]
  ushort_t* h2_pair  = (ushort_t*)slabA;  // [N][512]
  float*    support3 = (float*)slabB;     // [N][128]

  hipMemsetAsync(deg, 0, (size_t)N * 4, stream);
  int gE = (E + 255) / 256;
  deg_kernel<<<gE, 256, 0, stream>>>(edges, deg, E);
  scan_part_kernel<<<nBlocks, 256, 0, stream>>>(deg, partial, N);
  scan_top_kernel<<<1, 256, 0, stream>>>(partial, nBlocks);
  scan_fin_kernel<<<nBlocks, 256, 0, stream>>>(deg, partial, row_ptr, cursor, inv, N);
  scatter_kernel<<<gE, 256, 0, stream>>>(edges, cursor, colidx, E);
  sortrows_kernel<<<(N * 64 + 255) / 256, 256, 0, stream>>>(row_ptr, colidx, N);

  wprep_kernel<<<(128*256 + 255)/256, 256, 0, stream>>>(W1, wt1h, wt1l, 128, 256);
  wprep_kernel<<<(256*256 + 255)/256, 256, 0, stream>>>(W2, wt2h, wt2l, 256, 256);
  wprep_kernel<<<(256*128 + 255)/256, 256, 0, stream>>>(W3, wt3h, wt3l, 256, 128);

  int gm = (N + 127) / 128;
  dim3 g12(gm, 2);
  dim3 g3 (gm, 1);
  int gS64 = (N * 64 + 255) / 256;
  int gS32 = (N * 32 + 255) / 256;

  // layer 1 (reordered): t = A_hat x ; h1 = leaky(t@W1 + mask*b1)  [bf16 pair out]
  spmm128_pair_kernel<<<gS32, 256, 0, stream>>>(x, row_ptr, colidx, inv, t_pair, N);
  gemm_mfma_kernel<true><<<g12, 256, 0, stream>>>(t_pair, wt1h, wt1l, b1, inv,
                                                  nullptr, h1_pair, N, 128, 256);
  // layer 2: support2 = h1@W2 + b2 ; h2 = leaky(A_hat support2) [bf16 pair out]
  gemm_mfma_kernel<false><<<g12, 256, 0, stream>>>(h1_pair, wt2h, wt2l, b2, nullptr,
                                                   support2, nullptr, N, 256, 256);
  spmm256_leaky_pair_kernel<<<gS64, 256, 0, stream>>>(support2, row_ptr, colidx, inv, h2_pair, N);
  // layer 3: support3 = h2@W3 + b3 ; out = normalize(A_hat support3)
  gemm_mfma_kernel<false><<<g3, 256, 0, stream>>>(h2_pair, wt3h, wt3l, b3, nullptr,
                                                  support3, nullptr, N, 256, 128);
  spmm_norm_kernel<<<gS32, 256, 0, stream>>>(support3, row_ptr, colidx, inv, (float*)d_out, N);
}